// Round 5
// baseline (108.218 us; speedup 1.0000x reference)
//
#include <hip/hip_runtime.h>

// Lucas-Kanade optical flow — DIAGNOSTIC ROUND (r5).
// Identical math to round 4 (passed, absmax 0.0078), but gridDim.z = REPEAT:
// every z-slice computes and stores the SAME output bytes (idempotent, safe).
// Purpose: (1) push our dispatch above the harness's ~40us fill dispatches so
// it finally shows in rocprof top-5 (FETCH/WRITE/VALUBusy/Occupancy); (2)
// bench_dur = C + REPEAT*T and round4_dur = C + T lets us split fixed replay
// overhead C from true kernel time T.

#pragma clang fp contract(off)

typedef float v2f __attribute__((ext_vector_type(2)));

#define IMG_H 2048
#define IMG_W 2048
#define TW 32          // output cols per block
#define TH 32          // output rows per block
#define LDSW 36        // cols 0..31 interior, 32 = right halo, 34 = left halo
#define REPEAT 4       // diagnostic work multiplier (z-dim)

__global__ __launch_bounds__(256, 4)
void lk_flow_v5(const float* __restrict__ prev,
                const float* __restrict__ next,
                float* __restrict__ out) {
    #pragma clang fp contract(off)
    __shared__ __align__(16) float srx[TH + 2][LDSW];
    __shared__ __align__(16) float sry[TH + 2][LDSW];
    __shared__ __align__(16) float srt[TH + 2][LDSW];

    // blockIdx.z intentionally unused: all z-slices redo identical work and
    // store identical bytes to identical addresses (deterministic).
    const int r0 = (int)blockIdx.y * TH;
    const int c0 = (int)blockIdx.x * TW;
    const int tid = (int)threadIdx.y * 8 + (int)threadIdx.x;

    // ---- Phase A (interior): res rows r0-1+hr, 8 chunks of 4 aligned cols ----
    for (int t = tid; t < (TH + 2) * 8; t += 256) {
        const int hr = t >> 3;
        const int ch = t & 7;
        const int a  = r0 - 1 + hr;
        const int b  = c0 + ch * 4;
        float rx[4], ry[4], rt[4];
        if (a >= 0 && a < IMG_H) {
            const int a1 = (a + 1 == IMG_H) ? (IMG_H - 2) : (a + 1);  // reflect (after)
            const int b4 = (b + 4 == IMG_W) ? (IMG_W - 2) : (b + 4);  // reflect (after)
            const float4 P0 = *reinterpret_cast<const float4*>(&prev[(size_t)a  * IMG_W + b]);
            const float4 P1 = *reinterpret_cast<const float4*>(&prev[(size_t)a1 * IMG_W + b]);
            const float4 Q0 = *reinterpret_cast<const float4*>(&next[(size_t)a  * IMG_W + b]);
            const float4 Q1 = *reinterpret_cast<const float4*>(&next[(size_t)a1 * IMG_W + b]);
            const v2f m[5] = { {P0.x, Q0.x}, {P0.y, Q0.y}, {P0.z, Q0.z}, {P0.w, Q0.w},
                               {prev[(size_t)a  * IMG_W + b4], next[(size_t)a  * IMG_W + b4]} };
            const v2f n[5] = { {P1.x, Q1.x}, {P1.y, Q1.y}, {P1.z, Q1.z}, {P1.w, Q1.w},
                               {prev[(size_t)a1 * IMG_W + b4], next[(size_t)a1 * IMG_W + b4]} };
            #pragma unroll
            for (int k = 0; k < 4; ++k) {
                // bit-equal to reference left-to-right order (see r4 notes)
                const v2f A  = m[k] + m[k + 1];
                const v2f D  = m[k + 1] - m[k];
                const v2f GX = (D - n[k]) + n[k + 1];
                const v2f GY = (n[k] - A) + n[k + 1];
                const v2f GS = (A + n[k]) + n[k + 1];
                rx[k] = 0.5f * (GX.x + GX.y);
                ry[k] = 0.5f * (GY.x + GY.y);
                rt[k] = 0.5f * (GS.y - GS.x);
            }
        } else {
            #pragma unroll
            for (int k = 0; k < 4; ++k) { rx[k] = 0.f; ry[k] = 0.f; rt[k] = 0.f; }
        }
        const int lc = ch * 4;
        *reinterpret_cast<float4*>(&srx[hr][lc]) = make_float4(rx[0], rx[1], rx[2], rx[3]);
        *reinterpret_cast<float4*>(&sry[hr][lc]) = make_float4(ry[0], ry[1], ry[2], ry[3]);
        *reinterpret_cast<float4*>(&srt[hr][lc]) = make_float4(rt[0], rt[1], rt[2], rt[3]);
    }

    // ---- Phase A (edges): image col c0-1 -> LDS col 34, image col c0+32 -> LDS col 32
    for (int t = tid; t < (TH + 2) * 2; t += 256) {
        const int hr = t >> 1;
        const int e  = t & 1;
        const int a  = r0 - 1 + hr;
        const int bc = e ? (c0 + TW) : (c0 - 1);
        const int lc = e ? TW : 34;
        float rx = 0.f, ry = 0.f, rt = 0.f;
        if (a >= 0 && a < IMG_H && bc >= 0 && bc < IMG_W) {
            const int a1 = (a + 1 == IMG_H) ? (IMG_H - 2) : (a + 1);
            const int b1 = (bc + 1 == IMG_W) ? (IMG_W - 2) : (bc + 1);
            const v2f m0 = { prev[(size_t)a  * IMG_W + bc], next[(size_t)a  * IMG_W + bc] };
            const v2f m1 = { prev[(size_t)a  * IMG_W + b1], next[(size_t)a  * IMG_W + b1] };
            const v2f n0 = { prev[(size_t)a1 * IMG_W + bc], next[(size_t)a1 * IMG_W + bc] };
            const v2f n1 = { prev[(size_t)a1 * IMG_W + b1], next[(size_t)a1 * IMG_W + b1] };
            const v2f A  = m0 + m1;
            const v2f D  = m1 - m0;
            const v2f GX = (D - n0) + n1;
            const v2f GY = (n0 - A) + n1;
            const v2f GS = (A + n0) + n1;
            rx = 0.5f * (GX.x + GX.y);
            ry = 0.5f * (GY.x + GY.y);
            rt = 0.5f * (GS.y - GS.x);
        }
        srx[hr][lc] = rx; sry[hr][lc] = ry; srt[hr][lc] = rt;
    }

    __syncthreads();

    // ---- Phase B: each thread -> 1 output row x 4 output cols ----
    const int tx = (int)threadIdx.x;    // 0..7
    const int ty = (int)threadIdx.y;    // 0..31 = local output row
    const int jb = tx * 4;
    const int cm1 = (tx == 0) ? 34 : (jb - 1);

    v2f accA[4], accB[4];
    float accC[4];
    #pragma unroll
    for (int q = 0; q < 4; ++q) { accA[q] = (v2f){0.f, 0.f}; accB[q] = (v2f){0.f, 0.f}; accC[q] = 0.f; }

    #pragma unroll 1
    for (int rr = 0; rr < 3; ++rr) {
        const int hr = ty + rr;
        const float4 vx = *reinterpret_cast<const float4*>(&srx[hr][jb]);
        const float X[6] = { srx[hr][cm1], vx.x, vx.y, vx.z, vx.w, srx[hr][jb + 4] };
        const float4 vy = *reinterpret_cast<const float4*>(&sry[hr][jb]);
        const float Y[6] = { sry[hr][cm1], vy.x, vy.y, vy.z, vy.w, sry[hr][jb + 4] };
        const float4 vt = *reinterpret_cast<const float4*>(&srt[hr][jb]);
        const float T[6] = { srt[hr][cm1], vt.x, vt.y, vt.z, vt.w, srt[hr][jb + 4] };
        v2f PA[6], PB[6];
        float PC[6];
        #pragma unroll
        for (int k = 0; k < 6; ++k) {
            const v2f xy = { X[k], Y[k] };
            PA[k] = xy * xy;
            const v2f xt = { X[k], T[k] };
            const v2f yx = { Y[k], X[k] };
            PB[k] = xt * yx;
            PC[k] = T[k] * Y[k];
        }
        #pragma unroll
        for (int q = 0; q < 4; ++q) {
            accA[q] += PA[q]; accA[q] += PA[q + 1]; accA[q] += PA[q + 2];
            accB[q] += PB[q]; accB[q] += PB[q + 1]; accB[q] += PB[q + 2];
            accC[q] += PC[q]; accC[q] += PC[q + 1]; accC[q] += PC[q + 2];
        }
    }

    const int i = r0 + ty;
    float uo[4], vo[4];
    #pragma unroll
    for (int q = 0; q < 4; ++q) {
        const float Sxx = accA[q].x, Syy = accA[q].y;
        const float Sxy = accB[q].x, Sxt = accB[q].y;
        const float Syt = accC[q];
        const float t1 = Sxx * Syy;
        const float t2 = Sxy * Sxy;
        const float det = t1 - t2;
        float u = 0.f, v = 0.f;
        if (det != 0.f) {
            const float inv = __builtin_amdgcn_rcpf(det);
            const float n1 = Syy * Sxt - Sxy * Syt;
            const float n2 = Sxx * Syt - Sxy * Sxt;
            u = n1 * inv;
            v = n2 * inv;
        }
        const int j = c0 + jb + q;
        if (i == 0 || j == 0) { u = 0.f; v = 0.f; }
        uo[q] = u; vo[q] = v;
    }
    float4 U = {uo[0], uo[1], uo[2], uo[3]};
    float4 V = {vo[0], vo[1], vo[2], vo[3]};
    *reinterpret_cast<float4*>(&out[(size_t)i * IMG_W + (c0 + jb)]) = U;
    *reinterpret_cast<float4*>(&out[(size_t)(IMG_H + i) * IMG_W + (c0 + jb)]) = V;
}

extern "C" void kernel_launch(void* const* d_in, const int* in_sizes, int n_in,
                              void* d_out, int out_size, void* d_ws, size_t ws_size,
                              hipStream_t stream) {
    const float* prev = (const float*)d_in[0];
    const float* next = (const float*)d_in[1];
    float* out = (float*)d_out;
    dim3 grid(IMG_W / TW, IMG_H / TH, REPEAT);   // 64 x 64 x 4 (diagnostic)
    dim3 block(8, 32);
    lk_flow_v5<<<grid, block, 0, stream>>>(prev, next, out);
}

// Round 6
// 25.933 us; speedup vs baseline: 4.1730x; 4.1730x over previous
//
#include <hip/hip_runtime.h>

// Lucas-Kanade optical flow — r6: conflict-free LDS (stride 35, scalar b32),
// XCD-aware block remap, pointer-hoisted inner loop. Math/order identical to
// r4 (passed, absmax 0.0078125 = 73x under threshold).
// Input:  image_prev, image_next  (1,1,2048,2048) fp32
// Output: (1,2,2048,2048) fp32  -> u at [0:H*W], v at [H*W:2*H*W]

#pragma clang fp contract(off)

typedef float v2f __attribute__((ext_vector_type(2)));

#define IMG_H 2048
#define IMG_W 2048
#define TW 32          // output cols per block
#define TH 32          // output rows per block
// LDS row stride 35 dwords: 35 mod 32 = 3 -> bank = 3*row + col (mod 32);
// per-instruction lane banks are 2-way max (free). cols 0..31 interior,
// 32 = right halo (c0+32), 33 = left halo (c0-1), 34 = pad.
#define LDSW 35

__global__ __launch_bounds__(256, 4)
void lk_flow_v6(const float* __restrict__ prev,
                const float* __restrict__ next,
                float* __restrict__ out) {
    #pragma clang fp contract(off)
    __shared__ float srx[(TH + 2) * LDSW];
    __shared__ float sry[(TH + 2) * LDSW];
    __shared__ float srt[(TH + 2) * LDSW];

    // XCD-aware remap: HW round-robins linear workgroup id across 8 XCDs.
    // Give each XCD one contiguous band of 8 tile-rows (512 tiles) so halo
    // cache lines are shared within one XCD's L2. 4096 blocks % 8 == 0.
    const int lin = (int)blockIdx.y * (int)gridDim.x + (int)blockIdx.x;
    const int nl  = (lin >> 3) + (lin & 7) * 512;
    const int r0  = (nl >> 6) * TH;
    const int c0  = (nl & 63) * TW;

    const int tx  = (int)threadIdx.x;   // 0..7
    const int ty  = (int)threadIdx.y;   // 0..31
    const int tid = ty * 8 + tx;

    // ---- Phase A (interior): res rows r0-1+hr, 8 chunks of 4 aligned cols ----
    for (int t = tid; t < (TH + 2) * 8; t += 256) {
        const int hr = t >> 3;
        const int ch = t & 7;
        const int a  = r0 - 1 + hr;
        const int b  = c0 + ch * 4;
        float rx[4], ry[4], rt[4];
        if (a >= 0 && a < IMG_H) {
            const int a1 = (a + 1 == IMG_H) ? (IMG_H - 2) : (a + 1);  // reflect (after)
            const int b4 = (b + 4 == IMG_W) ? (IMG_W - 2) : (b + 4);  // reflect (after)
            const float4 P0 = *reinterpret_cast<const float4*>(&prev[(size_t)a  * IMG_W + b]);
            const float4 P1 = *reinterpret_cast<const float4*>(&prev[(size_t)a1 * IMG_W + b]);
            const float4 Q0 = *reinterpret_cast<const float4*>(&next[(size_t)a  * IMG_W + b]);
            const float4 Q1 = *reinterpret_cast<const float4*>(&next[(size_t)a1 * IMG_W + b]);
            const v2f m[5] = { {P0.x, Q0.x}, {P0.y, Q0.y}, {P0.z, Q0.z}, {P0.w, Q0.w},
                               {prev[(size_t)a  * IMG_W + b4], next[(size_t)a  * IMG_W + b4]} };
            const v2f n[5] = { {P1.x, Q1.x}, {P1.y, Q1.y}, {P1.z, Q1.z}, {P1.w, Q1.w},
                               {prev[(size_t)a1 * IMG_W + b4], next[(size_t)a1 * IMG_W + b4]} };
            #pragma unroll
            for (int k = 0; k < 4; ++k) {
                // bit-equal to reference left-to-right order:
                //   gx = ((p01-p00)-p10)+p11 ; gy = ((p10-(p00+p01))+p11 ; gs = ((p00+p01)+p10)+p11
                const v2f A  = m[k] + m[k + 1];
                const v2f D  = m[k + 1] - m[k];
                const v2f GX = (D - n[k]) + n[k + 1];
                const v2f GY = (n[k] - A) + n[k + 1];
                const v2f GS = (A + n[k]) + n[k + 1];
                rx[k] = 0.5f * (GX.x + GX.y);
                ry[k] = 0.5f * (GY.x + GY.y);
                rt[k] = 0.5f * (GS.y - GS.x);
            }
        } else {
            #pragma unroll
            for (int k = 0; k < 4; ++k) { rx[k] = 0.f; ry[k] = 0.f; rt[k] = 0.f; }
        }
        const int base = hr * LDSW + ch * 4;
        #pragma unroll
        for (int k = 0; k < 4; ++k) {   // bank = 3*hr + 4*ch + k: 2-way, free
            srx[base + k] = rx[k];
            sry[base + k] = ry[k];
            srt[base + k] = rt[k];
        }
    }

    // ---- Phase A (edges): image col c0+32 -> LDS col 32, image col c0-1 -> LDS col 33
    for (int t = tid; t < (TH + 2) * 2; t += 256) {
        const int hr = t >> 1;
        const int e  = t & 1;
        const int a  = r0 - 1 + hr;
        const int bc = e ? (c0 + TW) : (c0 - 1);
        const int lc = e ? 32 : 33;
        float rx = 0.f, ry = 0.f, rt = 0.f;
        if (a >= 0 && a < IMG_H && bc >= 0 && bc < IMG_W) {
            const int a1 = (a + 1 == IMG_H) ? (IMG_H - 2) : (a + 1);
            const int b1 = (bc + 1 == IMG_W) ? (IMG_W - 2) : (bc + 1);
            const v2f m0 = { prev[(size_t)a  * IMG_W + bc], next[(size_t)a  * IMG_W + bc] };
            const v2f m1 = { prev[(size_t)a  * IMG_W + b1], next[(size_t)a  * IMG_W + b1] };
            const v2f n0 = { prev[(size_t)a1 * IMG_W + bc], next[(size_t)a1 * IMG_W + bc] };
            const v2f n1 = { prev[(size_t)a1 * IMG_W + b1], next[(size_t)a1 * IMG_W + b1] };
            const v2f A  = m0 + m1;
            const v2f D  = m1 - m0;
            const v2f GX = (D - n0) + n1;
            const v2f GY = (n0 - A) + n1;
            const v2f GS = (A + n0) + n1;
            rx = 0.5f * (GX.x + GX.y);
            ry = 0.5f * (GY.x + GY.y);
            rt = 0.5f * (GS.y - GS.x);
        }
        const int o = hr * LDSW + lc;
        srx[o] = rx; sry[o] = ry; srt[o] = rt;
    }

    __syncthreads();

    // ---- Phase B: each thread -> 1 output row x 4 output cols, scalar b32 reads ----
    const int jb  = tx * 4;
    const int cm1 = (tx == 0) ? 33 : (jb - 1);   // LDS col of res col (c0+jb-1)

    const float* px = srx + ty * LDSW;
    const float* py = sry + ty * LDSW;
    const float* pt = srt + ty * LDSW;

    // packed accumulators: accA=(Sxx,Syy), accB=(Sxy,Sxt), accC=Syt
    v2f accA[4], accB[4];
    float accC[4];
    #pragma unroll
    for (int q = 0; q < 4; ++q) { accA[q] = (v2f){0.f, 0.f}; accB[q] = (v2f){0.f, 0.f}; accC[q] = 0.f; }

    #pragma unroll 1
    for (int rr = 0; rr < 3; ++rr) {
        // res cols (c0+jb-1) .. (c0+jb+4); bank = 3*row + col: 2-way max, free
        const float X[6] = { px[cm1], px[jb], px[jb+1], px[jb+2], px[jb+3], px[jb+4] };
        const float Y[6] = { py[cm1], py[jb], py[jb+1], py[jb+2], py[jb+3], py[jb+4] };
        const float T[6] = { pt[cm1], pt[jb], pt[jb+1], pt[jb+2], pt[jb+3], pt[jb+4] };
        px += LDSW; py += LDSW; pt += LDSW;
        v2f PA[6], PB[6];
        float PC[6];
        #pragma unroll
        for (int k = 0; k < 6; ++k) {
            const v2f xy = { X[k], Y[k] };
            PA[k] = xy * xy;                      // (rx*rx, ry*ry)
            const v2f xt = { X[k], T[k] };
            const v2f yx = { Y[k], X[k] };
            PB[k] = xt * yx;                      // (rx*ry, rt*rx)
            PC[k] = T[k] * Y[k];                  // rt*ry
        }
        // exact reference box3 order per output & array: dr outer (rr asc), dc inner
        #pragma unroll
        for (int q = 0; q < 4; ++q) {
            accA[q] += PA[q]; accA[q] += PA[q + 1]; accA[q] += PA[q + 2];
            accB[q] += PB[q]; accB[q] += PB[q + 1]; accB[q] += PB[q + 2];
            accC[q] += PC[q]; accC[q] += PC[q + 1]; accC[q] += PC[q + 2];
        }
    }

    const int i = r0 + ty;
    float uo[4], vo[4];
    #pragma unroll
    for (int q = 0; q < 4; ++q) {
        const float Sxx = accA[q].x, Syy = accA[q].y;
        const float Sxy = accB[q].x, Sxt = accB[q].y;
        const float Syt = accC[q];
        const float t1 = Sxx * Syy;
        const float t2 = Sxy * Sxy;
        const float det = t1 - t2;
        float u = 0.f, v = 0.f;
        if (det != 0.f) {
            const float inv = __builtin_amdgcn_rcpf(det);  // 1-ulp rcp, ample margin
            const float n1 = Syy * Sxt - Sxy * Syt;
            const float n2 = Sxx * Syt - Sxy * Sxt;
            u = n1 * inv;
            v = n2 * inv;
        }
        const int j = c0 + jb + q;
        if (i == 0 || j == 0) { u = 0.f; v = 0.f; }  // reference zeroes row0/col0
        uo[q] = u; vo[q] = v;
    }
    float4 U = {uo[0], uo[1], uo[2], uo[3]};
    float4 V = {vo[0], vo[1], vo[2], vo[3]};
    *reinterpret_cast<float4*>(&out[(size_t)i * IMG_W + (c0 + jb)]) = U;
    *reinterpret_cast<float4*>(&out[(size_t)(IMG_H + i) * IMG_W + (c0 + jb)]) = V;
}

extern "C" void kernel_launch(void* const* d_in, const int* in_sizes, int n_in,
                              void* d_out, int out_size, void* d_ws, size_t ws_size,
                              hipStream_t stream) {
    const float* prev = (const float*)d_in[0];
    const float* next = (const float*)d_in[1];
    float* out = (float*)d_out;
    dim3 grid(IMG_W / TW, IMG_H / TH);   // 64 x 64
    dim3 block(8, 32);
    lk_flow_v6<<<grid, block, 0, stream>>>(prev, next, out);
}

// Round 7
// 24.377 us; speedup vs baseline: 4.4393x; 1.0638x over previous
//
#include <hip/hip_runtime.h>

// Lucas-Kanade optical flow — r7: VALU-lean version.
// - interior fast path (no bounds/reflect for 94% of blocks), 32-bit addressing
// - scalar math (no forced v2f packing), identical op/rounding order to r6
// - column-shifted LDS: 6 consecutive dwords per Phase-B row -> ds_read2 merge
// Input:  image_prev, image_next  (1,1,2048,2048) fp32
// Output: (1,2,2048,2048) fp32  -> u at [0:H*W], v at [H*W:2*H*W]

#pragma clang fp contract(off)

#define IMG_H 2048
#define IMG_W 2048
#define TW 32
#define TH 32
// LDS col c holds res at image col (c0 + c - 1): 0 = left halo, 1..32 interior,
// 33 = right halo, 34 = pad. stride 35 (odd) -> bank = 3*row + col: 2-way, free.
#define LDSW 35

__global__ __launch_bounds__(256, 4)
void lk_flow_v7(const float* __restrict__ prev,
                const float* __restrict__ next,
                float* __restrict__ out) {
    #pragma clang fp contract(off)
    __shared__ float srx[(TH + 2) * LDSW];
    __shared__ float sry[(TH + 2) * LDSW];
    __shared__ float srt[(TH + 2) * LDSW];

    // XCD-aware remap (r6, kept): each XCD gets a contiguous band of 8 tile-rows.
    const int lin = (int)blockIdx.y * (int)gridDim.x + (int)blockIdx.x;
    const int nl  = (lin >> 3) + (lin & 7) * 512;
    const int r0  = (nl >> 6) * TH;
    const int c0  = (nl & 63) * TW;

    const int tx  = (int)threadIdx.x;   // 0..7
    const int ty  = (int)threadIdx.y;   // 0..31
    const int tid = ty * 8 + tx;

    // rows touched: r0-1 .. r0+33 (incl. a1); cols touched: c0-1 .. c0+33
    const bool interior = (r0 > 0) & (r0 + TH + 2 <= IMG_H - 1) &
                          (c0 > 0) & (c0 + TW + 2 <= IMG_W - 1);

    if (interior) {
        // ---- fast Phase A: no bounds checks, no reflect, int32 addressing ----
        // interior 4-col chunks: (hr, ch) -> image row r0-1+hr, cols c0+4ch..+4
        #pragma unroll
        for (int pass = 0; pass < 2; ++pass) {
            const int t = tid + pass * 256;
            if (pass == 0 || tid < 16) {          // 34*8 = 272 chunks
                const int hr = t >> 3;
                const int ch = t & 7;
                const int i0 = (r0 - 1 + hr) * IMG_W + (c0 + ch * 4);
                const int i1 = i0 + IMG_W;
                const float4 P0 = *reinterpret_cast<const float4*>(prev + i0);
                const float4 P1 = *reinterpret_cast<const float4*>(prev + i1);
                const float4 Q0 = *reinterpret_cast<const float4*>(next + i0);
                const float4 Q1 = *reinterpret_cast<const float4*>(next + i1);
                const float p0[5] = {P0.x, P0.y, P0.z, P0.w, prev[i0 + 4]};
                const float p1[5] = {P1.x, P1.y, P1.z, P1.w, prev[i1 + 4]};
                const float q0[5] = {Q0.x, Q0.y, Q0.z, Q0.w, next[i0 + 4]};
                const float q1[5] = {Q1.x, Q1.y, Q1.z, Q1.w, next[i1 + 4]};
                const int base = hr * LDSW + 1 + ch * 4;
                #pragma unroll
                for (int k = 0; k < 4; ++k) {
                    // bit-equal to reference left-to-right order:
                    //   gx=((p01-p00)-p10)+p11; gy=(p10-(p00+p01))+p11; gs=((p00+p01)+p10)+p11
                    const float Ap = p0[k] + p0[k + 1];
                    const float Aq = q0[k] + q0[k + 1];
                    const float gxp = ((p0[k + 1] - p0[k]) - p1[k]) + p1[k + 1];
                    const float gxq = ((q0[k + 1] - q0[k]) - q1[k]) + q1[k + 1];
                    const float gyp = (p1[k] - Ap) + p1[k + 1];
                    const float gyq = (q1[k] - Aq) + q1[k + 1];
                    const float gsp = (Ap + p1[k]) + p1[k + 1];
                    const float gsq = (Aq + q1[k]) + q1[k + 1];
                    srx[base + k] = 0.5f * (gxp + gxq);
                    sry[base + k] = 0.5f * (gyp + gyq);
                    srt[base + k] = 0.5f * (gsq - gsp);     // 0.5*(-gsp+gsq)
                }
            }
        }
        if (tid < 68) {   // edge cols: e=0 -> image c0-1 (LDS 0), e=1 -> c0+32 (LDS 33)
            const int hr = tid >> 1;
            const int e  = tid & 1;
            const int bc = e ? (c0 + TW) : (c0 - 1);
            const int i0 = (r0 - 1 + hr) * IMG_W + bc;
            const int i1 = i0 + IMG_W;
            const float p00 = prev[i0], p01 = prev[i0 + 1];
            const float p10 = prev[i1], p11 = prev[i1 + 1];
            const float q00 = next[i0], q01 = next[i0 + 1];
            const float q10 = next[i1], q11 = next[i1 + 1];
            const float Ap = p00 + p01, Aq = q00 + q01;
            const float gxp = ((p01 - p00) - p10) + p11;
            const float gxq = ((q01 - q00) - q10) + q11;
            const float gyp = (p10 - Ap) + p11;
            const float gyq = (q10 - Aq) + q11;
            const float gsp = (Ap + p10) + p11;
            const float gsq = (Aq + q10) + q11;
            const int o = hr * LDSW + (e ? 33 : 0);
            srx[o] = 0.5f * (gxp + gxq);
            sry[o] = 0.5f * (gyp + gyq);
            srt[o] = 0.5f * (gsq - gsp);
        }
    } else {
        // ---- slow Phase A: full bounds + reflect, scalar per LDS cell ----
        for (int t = tid; t < 34 * 34; t += 256) {
            const int hr = t / 34;
            const int c  = t - hr * 34;
            const int a  = r0 - 1 + hr;
            const int bc = c0 - 1 + c;
            float rx = 0.f, ry = 0.f, rt = 0.f;
            if (a >= 0 && a < IMG_H && bc >= 0 && bc < IMG_W) {
                const int a1 = (a + 1 == IMG_H) ? (IMG_H - 2) : (a + 1);   // reflect (after)
                const int b1 = (bc + 1 == IMG_W) ? (IMG_W - 2) : (bc + 1); // reflect (after)
                const int i0 = a * IMG_W, i1 = a1 * IMG_W;
                const float p00 = prev[i0 + bc], p01 = prev[i0 + b1];
                const float p10 = prev[i1 + bc], p11 = prev[i1 + b1];
                const float q00 = next[i0 + bc], q01 = next[i0 + b1];
                const float q10 = next[i1 + bc], q11 = next[i1 + b1];
                const float Ap = p00 + p01, Aq = q00 + q01;
                const float gxp = ((p01 - p00) - p10) + p11;
                const float gxq = ((q01 - q00) - q10) + q11;
                const float gyp = (p10 - Ap) + p11;
                const float gyq = (q10 - Aq) + q11;
                const float gsp = (Ap + p10) + p11;
                const float gsq = (Aq + q10) + q11;
                rx = 0.5f * (gxp + gxq);
                ry = 0.5f * (gyp + gyq);
                rt = 0.5f * (gsq - gsp);
            }
            const int o = hr * LDSW + c;
            srx[o] = rx; sry[o] = ry; srt[o] = rt;
        }
    }

    __syncthreads();

    // ---- Phase B: each thread -> 1 output row x 4 output cols ----
    // needs LDS cols 4tx .. 4tx+5 (image cols c0+4tx-1 .. c0+4tx+4): consecutive.
    const int jb = tx * 4;
    int off = ty * LDSW + jb;

    float aXX[4] = {0.f, 0.f, 0.f, 0.f};
    float aYY[4] = {0.f, 0.f, 0.f, 0.f};
    float aXY[4] = {0.f, 0.f, 0.f, 0.f};
    float aXT[4] = {0.f, 0.f, 0.f, 0.f};
    float aYT[4] = {0.f, 0.f, 0.f, 0.f};

    #pragma unroll
    for (int rr = 0; rr < 3; ++rr) {
        const float* px = srx + off;
        const float* py = sry + off;
        const float* pt = srt + off;
        float X[6], Y[6], T[6];
        #pragma unroll
        for (int k = 0; k < 6; ++k) { X[k] = px[k]; Y[k] = py[k]; T[k] = pt[k]; }
        off += LDSW;
        float xx[6], yy[6], xy[6], xt[6], yt[6];
        #pragma unroll
        for (int k = 0; k < 6; ++k) {
            xx[k] = X[k] * X[k];
            yy[k] = Y[k] * Y[k];
            xy[k] = X[k] * Y[k];
            xt[k] = T[k] * X[k];
            yt[k] = T[k] * Y[k];
        }
        // exact reference box3 order per output & array: dr outer (rr asc), dc inner
        #pragma unroll
        for (int q = 0; q < 4; ++q) {
            aXX[q] += xx[q]; aXX[q] += xx[q + 1]; aXX[q] += xx[q + 2];
            aYY[q] += yy[q]; aYY[q] += yy[q + 1]; aYY[q] += yy[q + 2];
            aXY[q] += xy[q]; aXY[q] += xy[q + 1]; aXY[q] += xy[q + 2];
            aXT[q] += xt[q]; aXT[q] += xt[q + 1]; aXT[q] += xt[q + 2];
            aYT[q] += yt[q]; aYT[q] += yt[q + 1]; aYT[q] += yt[q + 2];
        }
    }

    const int i = r0 + ty;
    float uo[4], vo[4];
    #pragma unroll
    for (int q = 0; q < 4; ++q) {
        const float Sxx = aXX[q], Syy = aYY[q], Sxy = aXY[q];
        const float Sxt = aXT[q], Syt = aYT[q];
        const float t1 = Sxx * Syy;
        const float t2 = Sxy * Sxy;
        const float det = t1 - t2;
        float u = 0.f, v = 0.f;
        if (det != 0.f) {
            const float inv = __builtin_amdgcn_rcpf(det);  // 1-ulp rcp, ample margin
            const float n1 = Syy * Sxt - Sxy * Syt;
            const float n2 = Sxx * Syt - Sxy * Sxt;
            u = n1 * inv;
            v = n2 * inv;
        }
        const int j = c0 + jb + q;
        if (i == 0 || j == 0) { u = 0.f; v = 0.f; }  // reference zeroes row0/col0
        uo[q] = u; vo[q] = v;
    }
    const int oidx = i * IMG_W + (c0 + jb);
    float4 U = {uo[0], uo[1], uo[2], uo[3]};
    float4 V = {vo[0], vo[1], vo[2], vo[3]};
    *reinterpret_cast<float4*>(out + oidx) = U;
    *reinterpret_cast<float4*>(out + IMG_H * IMG_W + oidx) = V;
}

extern "C" void kernel_launch(void* const* d_in, const int* in_sizes, int n_in,
                              void* d_out, int out_size, void* d_ws, size_t ws_size,
                              hipStream_t stream) {
    const float* prev = (const float*)d_in[0];
    const float* next = (const float*)d_in[1];
    float* out = (float*)d_out;
    dim3 grid(IMG_W / TW, IMG_H / TH);   // 64 x 64
    dim3 block(8, 32);
    lk_flow_v7<<<grid, block, 0, stream>>>(prev, next, out);
}